// Round 14
// baseline (159.999 us; speedup 1.0000x reference)
//
#include <hip/hip_runtime.h>

#define HWC 16384      // H*W
#define WD  128
#define NC  64
#define EPSV 1e-6f

typedef __attribute__((ext_vector_type(8))) short bf16x8;
typedef __attribute__((ext_vector_type(4))) float f32x4;
typedef __attribute__((ext_vector_type(4))) unsigned int u32x4;

__device__ __forceinline__ unsigned short f2bf(float f) {
  unsigned u = __builtin_bit_cast(unsigned, f);
  u = (u + 0x7FFFu + ((u >> 16) & 1u)) >> 16;   // RNE
  return (unsigned short)u;
}
__device__ __forceinline__ float bfLo(unsigned pk) { return __builtin_bit_cast(float, pk << 16); }
__device__ __forceinline__ float bfHi(unsigned pk) { return __builtin_bit_cast(float, pk & 0xFFFF0000u); }
// XOR swizzle for 128-B-row bf16 tiles.
__device__ __forceinline__ int swz(int row, int colbytes) {
  return ((row << 7) + colbytes) ^ ((row & 7) << 4);
}
__device__ __forceinline__ bf16x8 pack8(float4 a, float4 b) {
  bf16x8 r;
  r[0] = (short)f2bf(a.x); r[1] = (short)f2bf(a.y);
  r[2] = (short)f2bf(a.z); r[3] = (short)f2bf(a.w);
  r[4] = (short)f2bf(b.x); r[5] = (short)f2bf(b.y);
  r[6] = (short)f2bf(b.z); r[7] = (short)f2bf(b.w);
  return r;
}

// R10 structure, templated for phase ablation.
// V=0: full. V=1: skip stage+head (NMF reads uninitialized hl).
// V=2: skip NMF core (tap reads, pass1/2 VALU, 4-barrier reduce); dummy UV.
// Grid may be a multiple of 1024; replicas redo identical work (ws target).
template<int V>
__global__ __launch_bounds__(512) void k_abl(const float* __restrict__ x,
                                             const float* __restrict__ Wh,
                                             const float* __restrict__ Wt,
                                             float* __restrict__ outp) {
  __shared__ __align__(16) char smem[53248];
  unsigned short* xt = (unsigned short*)smem;            // [208 sites][64 c], 26624 B
  unsigned short* hl = (unsigned short*)(smem + 26624);  // [208 sites][64 o], 26624 B
  float* red = (float*)smem;                             // overlay (45056 B)
  unsigned short* uvb = (unsigned short*)smem;           // overlay (8192 B)

  const int t = threadIdx.x, lane = t & 63, wv = t >> 6;
  const int bid0 = blockIdx.x;
  const int cpx = gridDim.x >> 3;                        // XCD chunk size (grid%8==0)
  const int bidS = (bid0 & 7) * cpx + (bid0 >> 3);       // bijective XCD swizzle
  const int unit = bidS & 1023;                          // replica-folded work unit
  const int seg = unit & 1, y = (unit >> 1) & 127, b = unit >> 8;
  const int w0 = seg << 6;
  const int c0 = wv << 3;
  const int l15 = lane & 15, kg = lane >> 4;
  const int mt = wv & 3;
  const int mrow = (mt << 4) + l15;

  int gy[3];
  gy[0] = y >= 2 ? y - 2 : 0;
  gy[1] = y;
  gy[2] = y <= 125 ? y + 2 : 127;

  const float* xb = x + (size_t)b * (NC * HWC);

  if constexpr (V != 1) {
    // ---- head A fragments from global Wh ----
    bf16x8 ha0, ha1;
    {
      const float* wr = Wh + mrow * 64 + kg * 8;
      ha0 = pack8(*(const float4*)wr, *(const float4*)(wr + 4));
      ha1 = pack8(*(const float4*)(wr + 32), *(const float4*)(wr + 36));
    }
    // ---- stage xt[site][ch] ----
    {
      int colm = w0 - 2 + lane; if (colm < 0) colm = 0;
#pragma unroll
      for (int r = 0; r < 3; ++r) {
        const float* xr = xb + gy[r] * WD + colm;
        bf16x8 v;
#pragma unroll
        for (int u = 0; u < 8; ++u) v[u] = (short)f2bf(xr[(size_t)(c0 + u) * HWC]);
        *(bf16x8*)((char*)xt + swz(r * 68 + lane, c0 * 2)) = v;
      }
      if (lane < 12) {
        const int re = lane >> 2, e = lane & 3;
        int cole = w0 + 62 + e; if (cole > 127) cole = 127;
        const float* xr = xb + gy[re] * WD + cole;
        bf16x8 v;
#pragma unroll
        for (int u = 0; u < 8; ++u) v[u] = (short)f2bf(xr[(size_t)(c0 + u) * HWC]);
        *(bf16x8*)((char*)xt + swz(re * 68 + 64 + e, c0 * 2)) = v;
      }
    }
    __syncthreads();   // (1)

    // ---- head MFMA: 13 N-tiles x 4 M-tiles; ReLU; uint2 -> hl ----
    {
      const int ntBeg = (wv >> 2) ? 7 : 0;
      const int ntEnd = (wv >> 2) ? 13 : 7;
      const f32x4 z = {0.f, 0.f, 0.f, 0.f};
      for (int nt = ntBeg; nt < ntEnd; ++nt) {
        const int s = (nt << 4) + l15;
        const bf16x8 b0 = *(const bf16x8*)((char*)xt + swz(s, kg * 16));
        const bf16x8 b1 = *(const bf16x8*)((char*)xt + swz(s, 64 + kg * 16));
        f32x4 acc = __builtin_amdgcn_mfma_f32_16x16x32_bf16(ha0, b0, z, 0, 0, 0);
        acc = __builtin_amdgcn_mfma_f32_16x16x32_bf16(ha1, b1, acc, 0, 0, 0);
        const float v0 = acc[0] > 0.f ? acc[0] : 0.f;
        const float v1 = acc[1] > 0.f ? acc[1] : 0.f;
        const float v2 = acc[2] > 0.f ? acc[2] : 0.f;
        const float v3 = acc[3] > 0.f ? acc[3] : 0.f;
        uint2 pk2;
        pk2.x = (unsigned)f2bf(v0) | ((unsigned)f2bf(v1) << 16);
        pk2.y = (unsigned)f2bf(v2) | ((unsigned)f2bf(v3) << 16);
        *(uint2*)((char*)hl + swz(s, (mt * 16 + kg * 4) * 2)) = pk2;
      }
    }
    __syncthreads();   // (2)
  }

  if constexpr (V == 2) {
    // keep hl live (rule 17): opaque never-true guard
    int big = 4096;
    asm volatile("" : "+v"(big));
    if (t == big) outp[0] = (float)hl[0];
  }

  const int pl = lane;

  // ---- tail A fragments from global Wt (common) ----
  bf16x8 ta0, ta1;
  {
    const float* wr = Wt + mrow * 64 + kg * 8;
    ta0 = pack8(*(const float4*)wr, *(const float4*)(wr + 4));
    ta1 = pack8(*(const float4*)(wr + 32), *(const float4*)(wr + 36));
  }

  bf16x8 vv;
  if constexpr (V != 2) {
    // ---- NMF pass 1: 9 b128 tap reads; cache in regs ----
    u32x4 tap[9];
#pragma unroll
    for (int r = 0; r < 3; ++r)
#pragma unroll
      for (int kc = 0; kc < 3; ++kc)
        tap[r * 3 + kc] = *(const u32x4*)((char*)hl + swz(r * 68 + pl + 2 * kc, c0 * 2));

    float S = 0.f, sumk[9], A[9], mreg[8];
#pragma unroll
    for (int k = 0; k < 9; ++k) { sumk[k] = 0.f; A[k] = 0.f; }
#pragma unroll
    for (int c = 0; c < 8; ++c) {
      float tc[9];
#pragma unroll
      for (int k = 0; k < 9; ++k) {
        const unsigned w32 = tap[k][c >> 1];
        tc[k] = (c & 1) ? bfHi(w32) : bfLo(w32);
      }
      float m = 0.f;
#pragma unroll
      for (int k = 0; k < 9; ++k) m += tc[k];
      m *= (1.f / 9.f);
      mreg[c] = m;
      S += m * m;
#pragma unroll
      for (int k = 0; k < 9; ++k) { sumk[k] += tc[k]; A[k] += m * tc[k]; }
    }
    __syncthreads();   // hl reads done -> red overlay safe

    // ---- write 19 partials as float2 pairs (stride-22 cells) ----
    {
      float2* cell = (float2*)&red[t * 22];
      cell[0] = make_float2(S, sumk[0]);
      cell[1] = make_float2(sumk[1], sumk[2]);
      cell[2] = make_float2(sumk[3], sumk[4]);
      cell[3] = make_float2(sumk[5], sumk[6]);
      cell[4] = make_float2(sumk[7], sumk[8]);
      cell[5] = make_float2(A[0], A[1]);
      cell[6] = make_float2(A[2], A[3]);
      cell[7] = make_float2(A[4], A[5]);
      cell[8] = make_float2(A[6], A[7]);
      red[t * 22 + 18] = A[8];
    }
    __syncthreads();

    // ---- combine pair-slot p by wave p%8 ----
    for (int p = wv; p < 10; p += 8) {
      float2 f = {0.f, 0.f};
#pragma unroll
      for (int w2 = 0; w2 < 8; ++w2) {
        const float2 g = *(const float2*)&red[(w2 * 64 + lane) * 22 + 2 * p];
        f.x += g.x; f.y += g.y;
      }
      *(float2*)&red[lane * 22 + 2 * p] = f;
    }
    __syncthreads();

    // ---- finals -> Vk/T ----
    float Vk[9], T = 0.f;
    {
      const float2* cell = (const float2*)&red[lane * 22];
      const float2 d0 = cell[0], d1 = cell[1], d2 = cell[2], d3 = cell[3], d4 = cell[4];
      const float2 d5 = cell[5], d6 = cell[6], d7 = cell[7], d8 = cell[8];
      const float a8 = red[lane * 22 + 18];
      const float Sf = d0.x;
      const float sk[9] = {d0.y, d1.x, d1.y, d2.x, d2.y, d3.x, d3.y, d4.x, d4.y};
      const float Ak[9] = {d5.x, d5.y, d6.x, d6.y, d7.x, d7.y, d8.x, d8.y, a8};
#pragma unroll
      for (int k = 0; k < 9; ++k) {
        const float nk = sk[k] * (1.f / 64.f);
        Vk[k] = nk * (Ak[k] / (3.f * nk * Sf + EPSV));
        T += Vk[k] * Vk[k];
      }
    }
    const float V4 = Vk[4];
    __syncthreads();   // red reads done -> uvb overlay safe

    // ---- pass 2: pure VALU from cached taps ----
#pragma unroll
    for (int c = 0; c < 8; ++c) {
      float Bc = 0.f;
#pragma unroll
      for (int k = 0; k < 9; ++k) {
        const unsigned w32 = tap[k][c >> 1];
        const float tk = (c & 1) ? bfHi(w32) : bfLo(w32);
        Bc += tk * Vk[k];
      }
      const float m = mreg[c];
      const float Uc = m * (Bc / (3.f * m * T + EPSV));
      vv[c] = (short)f2bf(3.f * Uc * V4);
    }
  } else {
    vv = ta0;   // dummy UV, keeps tail running with live data
  }

  *(bf16x8*)((char*)uvb + swz(pl, c0 * 2)) = vv;   // [px][o]
  __syncthreads();   // (3)

  // ---- tail MFMA: M-tile mt, N-tiles {2*(wv>>2), +1}; + residual ----
  const int n0 = (wv >> 2) << 1;
  const f32x4 z2 = {0.f, 0.f, 0.f, 0.f};
  const size_t gb = (size_t)b * (NC * HWC) + (size_t)y * WD + w0;
#pragma unroll
  for (int nt = n0; nt < n0 + 2; ++nt) {
    const int px = (nt << 4) + l15;
    const bf16x8 b0 = *(const bf16x8*)((char*)uvb + swz(px, kg * 16));
    const bf16x8 b1 = *(const bf16x8*)((char*)uvb + swz(px, 64 + kg * 16));
    f32x4 acc = __builtin_amdgcn_mfma_f32_16x16x32_bf16(ta0, b0, z2, 0, 0, 0);
    acc = __builtin_amdgcn_mfma_f32_16x16x32_bf16(ta1, b1, acc, 0, 0, 0);
#pragma unroll
    for (int j = 0; j < 4; ++j) {
      const int c2 = (mt << 4) + kg * 4 + j;
      const size_t off = gb + (size_t)c2 * HWC + px;
      outp[off] = acc[j] + x[off];
    }
  }
}

extern "C" void kernel_launch(void* const* d_in, const int* in_sizes, int n_in,
                              void* d_out, int out_size, void* d_ws, size_t ws_size,
                              hipStream_t stream) {
  const float* x  = (const float*)d_in[0];
  const float* Wh = (const float*)d_in[1];
  const float* Wt = (const float*)d_in[2];
  float* out = (float*)d_out;
  float* ws  = (float*)d_ws;   // ablation sink (>= 16.8 MB)

  // --- ablation probes (replicated grids so they rank above fillBuffer) ---
  k_abl<1><<<4096, 512, 0, stream>>>(x, Wh, Wt, ws);  // no stage+head, x4
  k_abl<2><<<3072, 512, 0, stream>>>(x, Wh, Wt, ws);  // no NMF core,  x3
  k_abl<0><<<2048, 512, 0, stream>>>(x, Wh, Wt, ws);  // full,         x2
  // --- production dispatch (validated output) ---
  k_abl<0><<<1024, 512, 0, stream>>>(x, Wh, Wt, out);
}

// Round 16
// 25.706 us; speedup vs baseline: 6.2241x; 6.2241x over previous
//
#include <hip/hip_runtime.h>
#include <hip/hip_bf16.h>

#define HWC 16384      // H*W
#define WD  128
#define NC  64
#define EPSV 1e-6f

typedef __attribute__((ext_vector_type(8))) short bf16x8;
typedef __attribute__((ext_vector_type(4))) float f32x4;
typedef __attribute__((ext_vector_type(2))) float f32x2;
typedef __attribute__((ext_vector_type(4))) unsigned int u32x4;

// f32 pair -> packed bf16 (RNE, v_cvt_pk_bf16_f32)
__device__ __forceinline__ unsigned cvt2(float a, float b) {
  union { __hip_bfloat162 h; unsigned u; } r;
  r.h = __float22bfloat162_rn(make_float2(a, b));
  return r.u;
}
__device__ __forceinline__ float bfLo(unsigned pk) { return __builtin_bit_cast(float, pk << 16); }
__device__ __forceinline__ float bfHi(unsigned pk) { return __builtin_bit_cast(float, pk & 0xFFFF0000u); }
__device__ __forceinline__ f32x2 up2(unsigned w) {
  f32x2 r; r[0] = bfLo(w); r[1] = bfHi(w); return r;
}
// XOR swizzle for 128-B-row bf16 tiles.
__device__ __forceinline__ int swz(int row, int colbytes) {
  return ((row << 7) + colbytes) ^ ((row & 7) << 4);
}
__device__ __forceinline__ bf16x8 pack8(float4 a, float4 b) {
  union { unsigned u[4]; bf16x8 v; } r;
  r.u[0] = cvt2(a.x, a.y); r.u[1] = cvt2(a.z, a.w);
  r.u[2] = cvt2(b.x, b.y); r.u[3] = cvt2(b.z, b.w);
  return r.v;
}

// Fully fused head->NMF->tail (R10 structure, packed-VALU NMF core).
// grid 1024 (b,y,seg); 512 thr = 8 waves.
__global__ __launch_bounds__(512) void k_fused(const float* __restrict__ x,
                                               const float* __restrict__ Wh,
                                               const float* __restrict__ Wt,
                                               float* __restrict__ out) {
  __shared__ __align__(16) char smem[53248];
  unsigned short* xt = (unsigned short*)smem;            // [208 sites][64 c], 26624 B
  unsigned short* hl = (unsigned short*)(smem + 26624);  // [208 sites][64 o], 26624 B
  float* red = (float*)smem;                             // overlay (45056 B)
  unsigned short* uvb = (unsigned short*)smem;           // overlay (8192 B)

  const int t = threadIdx.x, lane = t & 63, wv = t >> 6;
  const int bid0 = blockIdx.x;
  const int bid = ((bid0 & 7) << 7) | (bid0 >> 3);  // XCD swizzle, bijective (1024%8==0)
  const int seg = bid & 1, y = (bid >> 1) & 127, b = bid >> 8;
  const int w0 = seg << 6;
  const int c0 = wv << 3;
  const int l15 = lane & 15, kg = lane >> 4;
  const int mt = wv & 3;
  const int mrow = (mt << 4) + l15;

  int gy[3];
  gy[0] = y >= 2 ? y - 2 : 0;
  gy[1] = y;
  gy[2] = y <= 125 ? y + 2 : 127;

  const float* xb = x + (size_t)b * (NC * HWC);

  // ---- head A fragments from global Wh (L2-resident) ----
  bf16x8 ha0, ha1;
  {
    const float* wr = Wh + mrow * 64 + kg * 8;
    ha0 = pack8(*(const float4*)wr, *(const float4*)(wr + 4));
    ha1 = pack8(*(const float4*)(wr + 32), *(const float4*)(wr + 36));
  }

  // ---- stage xt[site][ch] (cvt_pk pairs) ----
  {
    int colm = w0 - 2 + lane; if (colm < 0) colm = 0;
#pragma unroll
    for (int r = 0; r < 3; ++r) {
      const float* xr = xb + gy[r] * WD + colm;
      float f[8];
#pragma unroll
      for (int u = 0; u < 8; ++u) f[u] = xr[(size_t)(c0 + u) * HWC];
      u32x4 v;
      v[0] = cvt2(f[0], f[1]); v[1] = cvt2(f[2], f[3]);
      v[2] = cvt2(f[4], f[5]); v[3] = cvt2(f[6], f[7]);
      *(u32x4*)((char*)xt + swz(r * 68 + lane, c0 * 2)) = v;
    }
    if (lane < 12) {   // extra cols i=64..67
      const int re = lane >> 2, e = lane & 3;
      int cole = w0 + 62 + e; if (cole > 127) cole = 127;
      const float* xr = xb + gy[re] * WD + cole;
      float f[8];
#pragma unroll
      for (int u = 0; u < 8; ++u) f[u] = xr[(size_t)(c0 + u) * HWC];
      u32x4 v;
      v[0] = cvt2(f[0], f[1]); v[1] = cvt2(f[2], f[3]);
      v[2] = cvt2(f[4], f[5]); v[3] = cvt2(f[6], f[7]);
      *(u32x4*)((char*)xt + swz(re * 68 + 64 + e, c0 * 2)) = v;
    }
  }
  __syncthreads();   // (1)

  // ---- head MFMA: 13 N-tiles x 4 M-tiles; ReLU; cvt_pk -> hl ----
  {
    const int ntBeg = (wv >> 2) ? 7 : 0;
    const int ntEnd = (wv >> 2) ? 13 : 7;
    const f32x4 z = {0.f, 0.f, 0.f, 0.f};
    for (int nt = ntBeg; nt < ntEnd; ++nt) {
      const int s = (nt << 4) + l15;
      const bf16x8 b0 = *(const bf16x8*)((char*)xt + swz(s, kg * 16));
      const bf16x8 b1 = *(const bf16x8*)((char*)xt + swz(s, 64 + kg * 16));
      f32x4 acc = __builtin_amdgcn_mfma_f32_16x16x32_bf16(ha0, b0, z, 0, 0, 0);
      acc = __builtin_amdgcn_mfma_f32_16x16x32_bf16(ha1, b1, acc, 0, 0, 0);
      const float v0 = acc[0] > 0.f ? acc[0] : 0.f;
      const float v1 = acc[1] > 0.f ? acc[1] : 0.f;
      const float v2 = acc[2] > 0.f ? acc[2] : 0.f;
      const float v3 = acc[3] > 0.f ? acc[3] : 0.f;
      uint2 pk2;
      pk2.x = cvt2(v0, v1);
      pk2.y = cvt2(v2, v3);
      *(uint2*)((char*)hl + swz(s, (mt * 16 + kg * 4) * 2)) = pk2;
    }
  }
  __syncthreads();   // (2)

  const int pl = lane;

  // ---- NMF pass 1: 9 b128 tap reads; packed f32x2 accumulation ----
  u32x4 tap[9];
#pragma unroll
  for (int r = 0; r < 3; ++r)
#pragma unroll
    for (int kc = 0; kc < 3; ++kc)
      tap[r * 3 + kc] = *(const u32x4*)((char*)hl + swz(r * 68 + pl + 2 * kc, c0 * 2));

  f32x2 S2 = {0.f, 0.f};
  f32x2 sumk2[9], A2[9], mreg2[4];
#pragma unroll
  for (int k = 0; k < 9; ++k) { sumk2[k] = (f32x2){0.f, 0.f}; A2[k] = (f32x2){0.f, 0.f}; }
#pragma unroll
  for (int p = 0; p < 4; ++p) {      // channel pair p -> channels 2p, 2p+1
    f32x2 t2[9];
#pragma unroll
    for (int k = 0; k < 9; ++k) t2[k] = up2(tap[k][p]);
    f32x2 mm = t2[0];
#pragma unroll
    for (int k = 1; k < 9; ++k) mm += t2[k];
    mm *= (1.f / 9.f);
    mreg2[p] = mm;
    S2 += mm * mm;
#pragma unroll
    for (int k = 0; k < 9; ++k) { sumk2[k] += t2[k]; A2[k] += mm * t2[k]; }
  }
  const float S = S2[0] + S2[1];
  float sumk[9], A[9];
#pragma unroll
  for (int k = 0; k < 9; ++k) { sumk[k] = sumk2[k][0] + sumk2[k][1]; A[k] = A2[k][0] + A2[k][1]; }
  __syncthreads();   // hl reads done -> red overlay safe

  // ---- write 19 partials as float2 pairs (stride-22 cells) ----
  {
    float2* cell = (float2*)&red[t * 22];
    cell[0] = make_float2(S, sumk[0]);
    cell[1] = make_float2(sumk[1], sumk[2]);
    cell[2] = make_float2(sumk[3], sumk[4]);
    cell[3] = make_float2(sumk[5], sumk[6]);
    cell[4] = make_float2(sumk[7], sumk[8]);
    cell[5] = make_float2(A[0], A[1]);
    cell[6] = make_float2(A[2], A[3]);
    cell[7] = make_float2(A[4], A[5]);
    cell[8] = make_float2(A[6], A[7]);
    red[t * 22 + 18] = A[8];
  }
  __syncthreads();

  // ---- combine pair-slot p by wave p%8; finals land in cell[lane] ----
  for (int p = wv; p < 10; p += 8) {
    float2 f = {0.f, 0.f};
#pragma unroll
    for (int w2 = 0; w2 < 8; ++w2) {
      const float2 g = *(const float2*)&red[(w2 * 64 + lane) * 22 + 2 * p];
      f.x += g.x; f.y += g.y;
    }
    *(float2*)&red[lane * 22 + 2 * p] = f;
  }
  __syncthreads();

  // ---- every thread reads the 19 finals, computes Vk/T ----
  float Vk[9], T = 0.f;
  {
    const float2* cell = (const float2*)&red[lane * 22];
    const float2 d0 = cell[0], d1 = cell[1], d2 = cell[2], d3 = cell[3], d4 = cell[4];
    const float2 d5 = cell[5], d6 = cell[6], d7 = cell[7], d8 = cell[8];
    const float a8 = red[lane * 22 + 18];
    const float Sf = d0.x;
    const float sk[9] = {d0.y, d1.x, d1.y, d2.x, d2.y, d3.x, d3.y, d4.x, d4.y};
    const float Ak[9] = {d5.x, d5.y, d6.x, d6.y, d7.x, d7.y, d8.x, d8.y, a8};
#pragma unroll
    for (int k = 0; k < 9; ++k) {
      const float nk = sk[k] * (1.f / 64.f);
      Vk[k] = nk * (Ak[k] / (3.f * nk * Sf + EPSV));
      T += Vk[k] * Vk[k];
    }
  }
  const float V4 = Vk[4];
  __syncthreads();   // red reads done -> uvb overlay safe

  // ---- tail A fragments from global Wt (hides under pass 2) ----
  bf16x8 ta0, ta1;
  {
    const float* wr = Wt + mrow * 64 + kg * 8;
    ta0 = pack8(*(const float4*)wr, *(const float4*)(wr + 4));
    ta1 = pack8(*(const float4*)(wr + 32), *(const float4*)(wr + 36));
  }

  // ---- pass 2: packed f32x2 from cached taps; b128 UV write ----
  {
    u32x4 uvw;
#pragma unroll
    for (int p = 0; p < 4; ++p) {
      f32x2 B2 = {0.f, 0.f};
#pragma unroll
      for (int k = 0; k < 9; ++k) B2 += up2(tap[k][p]) * Vk[k];
      const f32x2 mm = mreg2[p];
      const f32x2 den = 3.f * mm * T + EPSV;
      const f32x2 Uc = mm * (B2 / den);
      const f32x2 uvv = 3.f * Uc * V4;
      uvw[p] = cvt2(uvv[0], uvv[1]);
    }
    *(u32x4*)((char*)uvb + swz(pl, c0 * 2)) = uvw;   // [px][o]
  }
  __syncthreads();   // (3)

  // ---- tail MFMA: M-tile mt, N-tiles {2*(wv>>2), +1}; + residual ----
  const int n0 = (wv >> 2) << 1;
  const f32x4 z2 = {0.f, 0.f, 0.f, 0.f};
  const size_t gb = (size_t)b * (NC * HWC) + (size_t)y * WD + w0;
#pragma unroll
  for (int nt = n0; nt < n0 + 2; ++nt) {
    const int px = (nt << 4) + l15;
    const bf16x8 b0 = *(const bf16x8*)((char*)uvb + swz(px, kg * 16));
    const bf16x8 b1 = *(const bf16x8*)((char*)uvb + swz(px, 64 + kg * 16));
    f32x4 acc = __builtin_amdgcn_mfma_f32_16x16x32_bf16(ta0, b0, z2, 0, 0, 0);
    acc = __builtin_amdgcn_mfma_f32_16x16x32_bf16(ta1, b1, acc, 0, 0, 0);
#pragma unroll
    for (int j = 0; j < 4; ++j) {
      const int c2 = (mt << 4) + kg * 4 + j;
      const size_t off = gb + (size_t)c2 * HWC + px;
      out[off] = acc[j] + x[off];
    }
  }
}

extern "C" void kernel_launch(void* const* d_in, const int* in_sizes, int n_in,
                              void* d_out, int out_size, void* d_ws, size_t ws_size,
                              hipStream_t stream) {
  const float* x  = (const float*)d_in[0];
  const float* Wh = (const float*)d_in[1];
  const float* Wt = (const float*)d_in[2];
  float* out = (float*)d_out;

  k_fused<<<1024, 512, 0, stream>>>(x, Wh, Wt, out);
}

// Round 17
// 25.668 us; speedup vs baseline: 6.2333x; 1.0015x over previous
//
#include <hip/hip_runtime.h>
#include <hip/hip_bf16.h>

#define HWC 16384      // H*W
#define WD  128
#define NC  64
#define EPSV 1e-6f

typedef __attribute__((ext_vector_type(8))) short bf16x8;
typedef __attribute__((ext_vector_type(4))) float f32x4;
typedef __attribute__((ext_vector_type(2))) float f32x2;
typedef __attribute__((ext_vector_type(4))) unsigned int u32x4;

// f32 pair -> packed bf16 (RNE, v_cvt_pk_bf16_f32)
__device__ __forceinline__ unsigned cvt2(float a, float b) {
  union { __hip_bfloat162 h; unsigned u; } r;
  r.h = __float22bfloat162_rn(make_float2(a, b));
  return r.u;
}
__device__ __forceinline__ float bfLo(unsigned pk) { return __builtin_bit_cast(float, pk << 16); }
__device__ __forceinline__ float bfHi(unsigned pk) { return __builtin_bit_cast(float, pk & 0xFFFF0000u); }
__device__ __forceinline__ f32x2 up2(unsigned w) {
  f32x2 r; r[0] = bfLo(w); r[1] = bfHi(w); return r;
}
// XOR swizzle for 128-B-row bf16 tiles.
__device__ __forceinline__ int swz(int row, int colbytes) {
  return ((row << 7) + colbytes) ^ ((row & 7) << 4);
}
__device__ __forceinline__ bf16x8 pack8(float4 a, float4 b) {
  union { unsigned u[4]; bf16x8 v; } r;
  r.u[0] = cvt2(a.x, a.y); r.u[1] = cvt2(a.z, a.w);
  r.u[2] = cvt2(b.x, b.y); r.u[3] = cvt2(b.z, b.w);
  return r.v;
}

// Fully fused head->NMF->tail. 3-barrier chain: NMF reduce = in-wave
// shfl_xor butterfly over 8-lane channel groups (taps from LDS, so lane
// mapping doesn't affect global coalescing). Packed f32x2 NMF VALU.
// grid 1024 (b,y,seg); 512 thr = 8 waves.
__global__ __launch_bounds__(512) void k_fused(const float* __restrict__ x,
                                               const float* __restrict__ Wh,
                                               const float* __restrict__ Wt,
                                               float* __restrict__ out) {
  __shared__ __align__(16) char smem[53248];
  unsigned short* xt = (unsigned short*)smem;            // [208 sites][64 c], 26624 B
  unsigned short* hl = (unsigned short*)(smem + 26624);  // [208 sites][64 o], 26624 B
  unsigned short* uvb = (unsigned short*)smem;           // overlay on xt (dead after head)

  const int t = threadIdx.x, lane = t & 63, wv = t >> 6;
  const int bid0 = blockIdx.x;
  const int bid = ((bid0 & 7) << 7) | (bid0 >> 3);  // XCD swizzle, bijective (1024%8==0)
  const int seg = bid & 1, y = (bid >> 1) & 127, b = bid >> 8;
  const int w0 = seg << 6;
  const int c0 = wv << 3;
  const int l15 = lane & 15, kg = lane >> 4;
  const int mt = wv & 3;
  const int mrow = (mt << 4) + l15;

  int gy[3];
  gy[0] = y >= 2 ? y - 2 : 0;
  gy[1] = y;
  gy[2] = y <= 125 ? y + 2 : 127;

  const float* xb = x + (size_t)b * (NC * HWC);

  // ---- head A fragments from global Wh (L2-resident) ----
  bf16x8 ha0, ha1;
  {
    const float* wr = Wh + mrow * 64 + kg * 8;
    ha0 = pack8(*(const float4*)wr, *(const float4*)(wr + 4));
    ha1 = pack8(*(const float4*)(wr + 32), *(const float4*)(wr + 36));
  }

  // ---- stage xt[site][ch] (cvt_pk pairs) ----
  {
    int colm = w0 - 2 + lane; if (colm < 0) colm = 0;
#pragma unroll
    for (int r = 0; r < 3; ++r) {
      const float* xr = xb + gy[r] * WD + colm;
      float f[8];
#pragma unroll
      for (int u = 0; u < 8; ++u) f[u] = xr[(size_t)(c0 + u) * HWC];
      u32x4 v;
      v[0] = cvt2(f[0], f[1]); v[1] = cvt2(f[2], f[3]);
      v[2] = cvt2(f[4], f[5]); v[3] = cvt2(f[6], f[7]);
      *(u32x4*)((char*)xt + swz(r * 68 + lane, c0 * 2)) = v;
    }
    if (lane < 12) {   // extra cols i=64..67
      const int re = lane >> 2, e = lane & 3;
      int cole = w0 + 62 + e; if (cole > 127) cole = 127;
      const float* xr = xb + gy[re] * WD + cole;
      float f[8];
#pragma unroll
      for (int u = 0; u < 8; ++u) f[u] = xr[(size_t)(c0 + u) * HWC];
      u32x4 v;
      v[0] = cvt2(f[0], f[1]); v[1] = cvt2(f[2], f[3]);
      v[2] = cvt2(f[4], f[5]); v[3] = cvt2(f[6], f[7]);
      *(u32x4*)((char*)xt + swz(re * 68 + 64 + e, c0 * 2)) = v;
    }
  }
  __syncthreads();   // (1)

  // ---- head MFMA: 13 N-tiles x 4 M-tiles; ReLU; cvt_pk -> hl ----
  {
    const int ntBeg = (wv >> 2) ? 7 : 0;
    const int ntEnd = (wv >> 2) ? 13 : 7;
    const f32x4 z = {0.f, 0.f, 0.f, 0.f};
    for (int nt = ntBeg; nt < ntEnd; ++nt) {
      const int s = (nt << 4) + l15;
      const bf16x8 b0 = *(const bf16x8*)((char*)xt + swz(s, kg * 16));
      const bf16x8 b1 = *(const bf16x8*)((char*)xt + swz(s, 64 + kg * 16));
      f32x4 acc = __builtin_amdgcn_mfma_f32_16x16x32_bf16(ha0, b0, z, 0, 0, 0);
      acc = __builtin_amdgcn_mfma_f32_16x16x32_bf16(ha1, b1, acc, 0, 0, 0);
      const float v0 = acc[0] > 0.f ? acc[0] : 0.f;
      const float v1 = acc[1] > 0.f ? acc[1] : 0.f;
      const float v2 = acc[2] > 0.f ? acc[2] : 0.f;
      const float v3 = acc[3] > 0.f ? acc[3] : 0.f;
      uint2 pk2;
      pk2.x = cvt2(v0, v1);
      pk2.y = cvt2(v2, v3);
      *(uint2*)((char*)hl + swz(s, (mt * 16 + kg * 4) * 2)) = pk2;
    }
  }
  __syncthreads();   // (2)

  // ================= NMF: thread = (px, channel-group cg) =================
  const int px = (wv << 3) | (lane >> 3);   // this thread's pixel
  const int cg16 = (lane & 7) << 4;         // channel-group colbytes (8 ch)

  // ---- pass 1: 9 b128 tap reads; packed f32x2 accumulation ----
  u32x4 tap[9];
#pragma unroll
  for (int r = 0; r < 3; ++r)
#pragma unroll
    for (int kc = 0; kc < 3; ++kc)
      tap[r * 3 + kc] = *(const u32x4*)((char*)hl + swz(r * 68 + px + 2 * kc, cg16));

  f32x2 S2 = {0.f, 0.f};
  f32x2 sumk2[9], A2[9], mreg2[4];
#pragma unroll
  for (int k = 0; k < 9; ++k) { sumk2[k] = (f32x2){0.f, 0.f}; A2[k] = (f32x2){0.f, 0.f}; }
#pragma unroll
  for (int p = 0; p < 4; ++p) {      // channel pair p within this cg
    f32x2 t2[9];
#pragma unroll
    for (int k = 0; k < 9; ++k) t2[k] = up2(tap[k][p]);
    f32x2 mm = t2[0];
#pragma unroll
    for (int k = 1; k < 9; ++k) mm += t2[k];
    mm *= (1.f / 9.f);
    mreg2[p] = mm;
    S2 += mm * mm;
#pragma unroll
    for (int k = 0; k < 9; ++k) { sumk2[k] += t2[k]; A2[k] += mm * t2[k]; }
  }
  float S = S2[0] + S2[1];
  float sumk[9], A[9];
#pragma unroll
  for (int k = 0; k < 9; ++k) { sumk[k] = sumk2[k][0] + sumk2[k][1]; A[k] = A2[k][0] + A2[k][1]; }

  // ---- butterfly reduce over the 8 channel-group lanes (xor 1,2,4) ----
#pragma unroll
  for (int d = 1; d <= 4; d <<= 1) {
    S += __shfl_xor(S, d);
#pragma unroll
    for (int k = 0; k < 9; ++k) sumk[k] += __shfl_xor(sumk[k], d);
#pragma unroll
    for (int k = 0; k < 9; ++k) A[k] += __shfl_xor(A[k], d);
  }

  float Vk[9], T = 0.f;
#pragma unroll
  for (int k = 0; k < 9; ++k) {
    const float nk = sumk[k] * (1.f / 64.f);
    Vk[k] = nk * (A[k] / (3.f * nk * S + EPSV));
    T += Vk[k] * Vk[k];
  }
  const float V4 = Vk[4];

  // ---- tail A fragments from global Wt (hides under pass 2) ----
  bf16x8 ta0, ta1;
  {
    const float* wr = Wt + mrow * 64 + kg * 8;
    ta0 = pack8(*(const float4*)wr, *(const float4*)(wr + 4));
    ta1 = pack8(*(const float4*)(wr + 32), *(const float4*)(wr + 36));
  }

  // ---- pass 2: packed f32x2 from cached taps; b128 UV write ----
  {
    u32x4 uvw;
#pragma unroll
    for (int p = 0; p < 4; ++p) {
      f32x2 B2 = {0.f, 0.f};
#pragma unroll
      for (int k = 0; k < 9; ++k) B2 += up2(tap[k][p]) * Vk[k];
      const f32x2 mm = mreg2[p];
      const f32x2 den = 3.f * mm * T + EPSV;
      const f32x2 Uc = mm * (B2 / den);
      const f32x2 uvv = 3.f * Uc * V4;
      uvw[p] = cvt2(uvv[0], uvv[1]);
    }
    *(u32x4*)((char*)uvb + swz(px, cg16)) = uvw;   // [px][o]
  }
  __syncthreads();   // (3)

  // ---- tail MFMA: M-tile mt, N-tiles {2*(wv>>2), +1}; + residual ----
  const int n0 = (wv >> 2) << 1;
  const f32x4 z2 = {0.f, 0.f, 0.f, 0.f};
  const size_t gb = (size_t)b * (NC * HWC) + (size_t)y * WD + w0;
#pragma unroll
  for (int nt = n0; nt < n0 + 2; ++nt) {
    const int pxs = (nt << 4) + l15;
    const bf16x8 b0 = *(const bf16x8*)((char*)uvb + swz(pxs, kg * 16));
    const bf16x8 b1 = *(const bf16x8*)((char*)uvb + swz(pxs, 64 + kg * 16));
    f32x4 acc = __builtin_amdgcn_mfma_f32_16x16x32_bf16(ta0, b0, z2, 0, 0, 0);
    acc = __builtin_amdgcn_mfma_f32_16x16x32_bf16(ta1, b1, acc, 0, 0, 0);
#pragma unroll
    for (int j = 0; j < 4; ++j) {
      const int c2 = (mt << 4) + kg * 4 + j;
      const size_t off = gb + (size_t)c2 * HWC + pxs;
      out[off] = acc[j] + x[off];
    }
  }
}

extern "C" void kernel_launch(void* const* d_in, const int* in_sizes, int n_in,
                              void* d_out, int out_size, void* d_ws, size_t ws_size,
                              hipStream_t stream) {
  const float* x  = (const float*)d_in[0];
  const float* Wh = (const float*)d_in[1];
  const float* Wt = (const float*)d_in[2];
  float* out = (float*)d_out;

  k_fused<<<1024, 512, 0, stream>>>(x, Wh, Wt, out);
}

// Round 18
// 24.126 us; speedup vs baseline: 6.6318x; 1.0639x over previous
//
#include <hip/hip_runtime.h>
#include <hip/hip_bf16.h>

#define HWC 16384      // H*W
#define WD  128
#define NC  64
#define EPSV 1e-6f

typedef __attribute__((ext_vector_type(8))) short bf16x8;
typedef __attribute__((ext_vector_type(4))) float f32x4;
typedef __attribute__((ext_vector_type(2))) float f32x2;
typedef __attribute__((ext_vector_type(4))) unsigned int u32x4;

// f32 pair -> packed bf16 (RNE, v_cvt_pk_bf16_f32)
__device__ __forceinline__ unsigned cvt2(float a, float b) {
  union { __hip_bfloat162 h; unsigned u; } r;
  r.h = __float22bfloat162_rn(make_float2(a, b));
  return r.u;
}
__device__ __forceinline__ float bfLo(unsigned pk) { return __builtin_bit_cast(float, pk << 16); }
__device__ __forceinline__ float bfHi(unsigned pk) { return __builtin_bit_cast(float, pk & 0xFFFF0000u); }
__device__ __forceinline__ f32x2 up2(unsigned w) {
  f32x2 r; r[0] = bfLo(w); r[1] = bfHi(w); return r;
}
// fast reciprocal (v_rcp_f32, ~1 ulp) — absmax headroom is 3x, error ~1e-7
__device__ __forceinline__ float frcp(float x) { return __builtin_amdgcn_rcpf(x); }
// XOR swizzle for 128-B-row bf16 tiles.
__device__ __forceinline__ int swz(int row, int colbytes) {
  return ((row << 7) + colbytes) ^ ((row & 7) << 4);
}
__device__ __forceinline__ bf16x8 pack8(float4 a, float4 b) {
  union { unsigned u[4]; bf16x8 v; } r;
  r.u[0] = cvt2(a.x, a.y); r.u[1] = cvt2(a.z, a.w);
  r.u[2] = cvt2(b.x, b.y); r.u[3] = cvt2(b.z, b.w);
  return r.v;
}

// Fully fused head->NMF->tail. 3 barriers; in-wave shfl_xor NMF reduce;
// packed f32x2 NMF VALU; fast-rcp for all divisions.
// grid 1024 (b,y,seg); 512 thr = 8 waves.
__global__ __launch_bounds__(512) void k_fused(const float* __restrict__ x,
                                               const float* __restrict__ Wh,
                                               const float* __restrict__ Wt,
                                               float* __restrict__ out) {
  __shared__ __align__(16) char smem[53248];
  unsigned short* xt = (unsigned short*)smem;            // [208 sites][64 c], 26624 B
  unsigned short* hl = (unsigned short*)(smem + 26624);  // [208 sites][64 o], 26624 B
  unsigned short* uvb = (unsigned short*)smem;           // overlay on xt (dead after head)

  const int t = threadIdx.x, lane = t & 63, wv = t >> 6;
  const int bid0 = blockIdx.x;
  const int bid = ((bid0 & 7) << 7) | (bid0 >> 3);  // XCD swizzle, bijective (1024%8==0)
  const int seg = bid & 1, y = (bid >> 1) & 127, b = bid >> 8;
  const int w0 = seg << 6;
  const int c0 = wv << 3;
  const int l15 = lane & 15, kg = lane >> 4;
  const int mt = wv & 3;
  const int mrow = (mt << 4) + l15;

  int gy[3];
  gy[0] = y >= 2 ? y - 2 : 0;
  gy[1] = y;
  gy[2] = y <= 125 ? y + 2 : 127;

  const float* xb = x + (size_t)b * (NC * HWC);

  // ---- head A fragments from global Wh (L2-resident) ----
  bf16x8 ha0, ha1;
  {
    const float* wr = Wh + mrow * 64 + kg * 8;
    ha0 = pack8(*(const float4*)wr, *(const float4*)(wr + 4));
    ha1 = pack8(*(const float4*)(wr + 32), *(const float4*)(wr + 36));
  }

  // ---- stage xt[site][ch] (cvt_pk pairs) ----
  {
    int colm = w0 - 2 + lane; if (colm < 0) colm = 0;
#pragma unroll
    for (int r = 0; r < 3; ++r) {
      const float* xr = xb + gy[r] * WD + colm;
      float f[8];
#pragma unroll
      for (int u = 0; u < 8; ++u) f[u] = xr[(size_t)(c0 + u) * HWC];
      u32x4 v;
      v[0] = cvt2(f[0], f[1]); v[1] = cvt2(f[2], f[3]);
      v[2] = cvt2(f[4], f[5]); v[3] = cvt2(f[6], f[7]);
      *(u32x4*)((char*)xt + swz(r * 68 + lane, c0 * 2)) = v;
    }
    if (lane < 12) {   // extra cols i=64..67
      const int re = lane >> 2, e = lane & 3;
      int cole = w0 + 62 + e; if (cole > 127) cole = 127;
      const float* xr = xb + gy[re] * WD + cole;
      float f[8];
#pragma unroll
      for (int u = 0; u < 8; ++u) f[u] = xr[(size_t)(c0 + u) * HWC];
      u32x4 v;
      v[0] = cvt2(f[0], f[1]); v[1] = cvt2(f[2], f[3]);
      v[2] = cvt2(f[4], f[5]); v[3] = cvt2(f[6], f[7]);
      *(u32x4*)((char*)xt + swz(re * 68 + 64 + e, c0 * 2)) = v;
    }
  }
  __syncthreads();   // (1)

  // ---- head MFMA: 13 N-tiles x 4 M-tiles; ReLU; cvt_pk -> hl ----
  {
    const int ntBeg = (wv >> 2) ? 7 : 0;
    const int ntEnd = (wv >> 2) ? 13 : 7;
    const f32x4 z = {0.f, 0.f, 0.f, 0.f};
    for (int nt = ntBeg; nt < ntEnd; ++nt) {
      const int s = (nt << 4) + l15;
      const bf16x8 b0 = *(const bf16x8*)((char*)xt + swz(s, kg * 16));
      const bf16x8 b1 = *(const bf16x8*)((char*)xt + swz(s, 64 + kg * 16));
      f32x4 acc = __builtin_amdgcn_mfma_f32_16x16x32_bf16(ha0, b0, z, 0, 0, 0);
      acc = __builtin_amdgcn_mfma_f32_16x16x32_bf16(ha1, b1, acc, 0, 0, 0);
      const float v0 = acc[0] > 0.f ? acc[0] : 0.f;
      const float v1 = acc[1] > 0.f ? acc[1] : 0.f;
      const float v2 = acc[2] > 0.f ? acc[2] : 0.f;
      const float v3 = acc[3] > 0.f ? acc[3] : 0.f;
      uint2 pk2;
      pk2.x = cvt2(v0, v1);
      pk2.y = cvt2(v2, v3);
      *(uint2*)((char*)hl + swz(s, (mt * 16 + kg * 4) * 2)) = pk2;
    }
  }
  __syncthreads();   // (2)

  // ================= NMF: thread = (px, channel-group cg) =================
  const int px = (wv << 3) | (lane >> 3);   // this thread's pixel
  const int cg16 = (lane & 7) << 4;         // channel-group colbytes (8 ch)

  // ---- pass 1: 9 b128 tap reads; packed f32x2 accumulation ----
  u32x4 tap[9];
#pragma unroll
  for (int r = 0; r < 3; ++r)
#pragma unroll
    for (int kc = 0; kc < 3; ++kc)
      tap[r * 3 + kc] = *(const u32x4*)((char*)hl + swz(r * 68 + px + 2 * kc, cg16));

  f32x2 S2 = {0.f, 0.f};
  f32x2 sumk2[9], A2[9], mreg2[4];
#pragma unroll
  for (int k = 0; k < 9; ++k) { sumk2[k] = (f32x2){0.f, 0.f}; A2[k] = (f32x2){0.f, 0.f}; }
#pragma unroll
  for (int p = 0; p < 4; ++p) {      // channel pair p within this cg
    f32x2 t2[9];
#pragma unroll
    for (int k = 0; k < 9; ++k) t2[k] = up2(tap[k][p]);
    f32x2 mm = t2[0];
#pragma unroll
    for (int k = 1; k < 9; ++k) mm += t2[k];
    mm *= (1.f / 9.f);
    mreg2[p] = mm;
    S2 += mm * mm;
#pragma unroll
    for (int k = 0; k < 9; ++k) { sumk2[k] += t2[k]; A2[k] += mm * t2[k]; }
  }
  float S = S2[0] + S2[1];
  float sumk[9], A[9];
#pragma unroll
  for (int k = 0; k < 9; ++k) { sumk[k] = sumk2[k][0] + sumk2[k][1]; A[k] = A2[k][0] + A2[k][1]; }

  // ---- butterfly reduce over the 8 channel-group lanes (xor 1,2,4) ----
#pragma unroll
  for (int d = 1; d <= 4; d <<= 1) {
    S += __shfl_xor(S, d);
#pragma unroll
    for (int k = 0; k < 9; ++k) sumk[k] += __shfl_xor(sumk[k], d);
#pragma unroll
    for (int k = 0; k < 9; ++k) A[k] += __shfl_xor(A[k], d);
  }

  float Vk[9], T = 0.f;
#pragma unroll
  for (int k = 0; k < 9; ++k) {
    const float nk = sumk[k] * (1.f / 64.f);
    Vk[k] = nk * A[k] * frcp(3.f * nk * S + EPSV);   // fast rcp
    T += Vk[k] * Vk[k];
  }
  const float V4 = Vk[4];

  // ---- tail A fragments from global Wt (hides under pass 2) ----
  bf16x8 ta0, ta1;
  {
    const float* wr = Wt + mrow * 64 + kg * 8;
    ta0 = pack8(*(const float4*)wr, *(const float4*)(wr + 4));
    ta1 = pack8(*(const float4*)(wr + 32), *(const float4*)(wr + 36));
  }

  // ---- pass 2: packed f32x2 from cached taps; fast rcp; b128 UV write ----
  {
    u32x4 uvw;
#pragma unroll
    for (int p = 0; p < 4; ++p) {
      f32x2 B2 = {0.f, 0.f};
#pragma unroll
      for (int k = 0; k < 9; ++k) B2 += up2(tap[k][p]) * Vk[k];
      const f32x2 mm = mreg2[p];
      f32x2 rden;
      rden[0] = frcp(3.f * mm[0] * T + EPSV);
      rden[1] = frcp(3.f * mm[1] * T + EPSV);
      const f32x2 Uc = mm * B2 * rden;
      const f32x2 uvv = 3.f * Uc * V4;
      uvw[p] = cvt2(uvv[0], uvv[1]);
    }
    *(u32x4*)((char*)uvb + swz(px, cg16)) = uvw;   // [px][o]
  }
  __syncthreads();   // (3)

  // ---- tail MFMA: M-tile mt, N-tiles {2*(wv>>2), +1}; + residual ----
  const int n0 = (wv >> 2) << 1;
  const f32x4 z2 = {0.f, 0.f, 0.f, 0.f};
  const size_t gb = (size_t)b * (NC * HWC) + (size_t)y * WD + w0;
#pragma unroll
  for (int nt = n0; nt < n0 + 2; ++nt) {
    const int pxs = (nt << 4) + l15;
    const bf16x8 b0 = *(const bf16x8*)((char*)uvb + swz(pxs, kg * 16));
    const bf16x8 b1 = *(const bf16x8*)((char*)uvb + swz(pxs, 64 + kg * 16));
    f32x4 acc = __builtin_amdgcn_mfma_f32_16x16x32_bf16(ta0, b0, z2, 0, 0, 0);
    acc = __builtin_amdgcn_mfma_f32_16x16x32_bf16(ta1, b1, acc, 0, 0, 0);
#pragma unroll
    for (int j = 0; j < 4; ++j) {
      const int c2 = (mt << 4) + kg * 4 + j;
      const size_t off = gb + (size_t)c2 * HWC + pxs;
      out[off] = acc[j] + x[off];
    }
  }
}

extern "C" void kernel_launch(void* const* d_in, const int* in_sizes, int n_in,
                              void* d_out, int out_size, void* d_ws, size_t ws_size,
                              hipStream_t stream) {
  const float* x  = (const float*)d_in[0];
  const float* Wh = (const float*)d_in[1];
  const float* Wt = (const float*)d_in[2];
  float* out = (float*)d_out;

  k_fused<<<1024, 512, 0, stream>>>(x, Wh, Wt, out);
}